// Round 1
// baseline (319.096 us; speedup 1.0000x reference)
//
#include <hip/hip_runtime.h>
#include <hip/hip_bf16.h>

typedef __bf16 bf16_t;
typedef __bf16 bf16x8 __attribute__((ext_vector_type(8)));
typedef float f32x4 __attribute__((ext_vector_type(4)));

#define B_   2
#define N_   16384
#define S_   4096
#define DS_  128
#define DT_  256
#define CIN_ 384
#define C0_  256
#define C1_  128
#define M_   (B_*N_)      // 32768 points total
#define NCH_ 4
#define SCH_ (S_/NCH_)    // 1024 targets per chunk

__device__ __forceinline__ void gl_lds16(const void* g, void* l) {
  __builtin_amdgcn_global_load_lds((const __attribute__((address_space(1))) void*)g,
                                   (__attribute__((address_space(3))) void*)l, 16, 0, 0);
}

// top-3 insertion, strict < keeps earliest index on ties (matches lax.top_k)
__device__ __forceinline__ void ins3(float d, int ix,
                                     float& d0, float& d1, float& d2,
                                     int& i0, int& i1, int& i2) {
  if (d < d2) {
    if (d < d1) {
      d2 = d1; i2 = i1;
      if (d < d0) { d1 = d0; i1 = i0; d0 = d; i0 = ix; }
      else        { d1 = d;  i1 = ix; }
    } else { d2 = d; i2 = ix; }
  }
}

// ---------------- weights fp32 -> bf16 ----------------
__global__ void k_convw(const float* __restrict__ w0, const float* __restrict__ w1,
                        bf16_t* __restrict__ w0b, bf16_t* __restrict__ w1b) {
  int i = blockIdx.x * 256 + threadIdx.x;          // grid covers 98304 exactly
  if (i < C0_*CIN_) w0b[i] = (bf16_t)w0[i];
  if (i < C1_*C0_)  w1b[i] = (bf16_t)w1[i];
}

// ---------------- 3-NN over one target chunk ----------------
// Exact numpy fp32 order: d = ((sx2+sy2)+sz2 + (tx2+ty2)+tz2) - 2*((sx tx + sy ty) + sz tz)
__global__ __launch_bounds__(256) void k_knn(const float* __restrict__ xyz_s,
                                             const float* __restrict__ xyz_t,
                                             float* __restrict__ pd, int* __restrict__ pi) {
  __shared__ float4 tgt[SCH_];
  const int b = blockIdx.z, ch = blockIdx.y;
  const int n = blockIdx.x * 256 + threadIdx.x;
  const int s0 = ch * SCH_;
  for (int j = threadIdx.x; j < SCH_; j += 256) {
    const float* q = xyz_t + ((size_t)b*S_ + s0 + j)*3;
    float x = q[0], y = q[1], z = q[2];
    float t2 = __fadd_rn(__fadd_rn(__fmul_rn(x,x), __fmul_rn(y,y)), __fmul_rn(z,z));
    tgt[j] = make_float4(x, y, z, t2);
  }
  __syncthreads();
  const float* ps = xyz_s + ((size_t)b*N_ + n)*3;
  const float sx = ps[0], sy = ps[1], sz = ps[2];
  const float s2 = __fadd_rn(__fadd_rn(__fmul_rn(sx,sx), __fmul_rn(sy,sy)), __fmul_rn(sz,sz));
  float d0 = 3.4e38f, d1 = 3.4e38f, d2 = 3.4e38f;
  int   i0 = 0, i1 = 0, i2 = 0;
  #pragma unroll 4
  for (int j = 0; j < SCH_; ++j) {
    float4 t = tgt[j];
    float dot = __fadd_rn(__fadd_rn(__fmul_rn(sx,t.x), __fmul_rn(sy,t.y)), __fmul_rn(sz,t.z));
    float d   = __fsub_rn(__fadd_rn(s2, t.w), __fmul_rn(2.f, dot));
    ins3(d, j, d0, d1, d2, i0, i1, i2);
  }
  size_t base = ((size_t)(b*N_ + n)*NCH_ + ch)*3;
  pd[base+0] = d0; pd[base+1] = d1; pd[base+2] = d2;
  pi[base+0] = s0+i0; pi[base+1] = s0+i1; pi[base+2] = s0+i2;
}

// ---------------- merge chunk candidates, compute inverse-distance weights ----------------
__global__ void k_merge(const float* __restrict__ pd, const int* __restrict__ pi,
                        float* __restrict__ wgt, int* __restrict__ widx) {
  int p = blockIdx.x * 256 + threadIdx.x;  // 0..32767
  float d0 = 3.4e38f, d1 = 3.4e38f, d2 = 3.4e38f;
  int   i0 = 0, i1 = 0, i2 = 0;
  size_t base = (size_t)p * (NCH_*3);
  #pragma unroll
  for (int c = 0; c < NCH_*3; ++c)        // chunk-major = ascending target index
    ins3(pd[base+c], pi[base+c], d0, d1, d2, i0, i1, i2);
  float r0 = 1.f/(d0 + 1e-8f), r1 = 1.f/(d1 + 1e-8f), r2 = 1.f/(d2 + 1e-8f);
  float s = r0 + r1 + r2;
  wgt[p*3+0] = r0/s; wgt[p*3+1] = r1/s; wgt[p*3+2] = r2/s;
  widx[p*3+0] = i0;  widx[p*3+1] = i1;  widx[p*3+2] = i2;
}

// ---------------- gather + interpolate + concat -> features (bf16, [M][384]) ----------------
__global__ __launch_bounds__(256) void k_gather(const float* __restrict__ feats_s,
                                                const float* __restrict__ feats_t,
                                                const float* __restrict__ wgt,
                                                const int* __restrict__ widx,
                                                bf16_t* __restrict__ features) {
  const int g = threadIdx.x >> 5, lane = threadIdx.x & 31;
  const int p = blockIdx.x * 8 + g;
  const int b = p >> 14;                       // N_ = 2^14
  const float w0 = wgt[p*3+0], w1 = wgt[p*3+1], w2 = wgt[p*3+2];
  const int   j0 = widx[p*3+0], j1 = widx[p*3+1], j2 = widx[p*3+2];
  const float* f0 = feats_t + ((size_t)b*S_ + j0)*DT_;
  const float* f1 = feats_t + ((size_t)b*S_ + j1)*DT_;
  const float* f2 = feats_t + ((size_t)b*S_ + j2)*DT_;
  const float* fs = feats_s + (size_t)p*DS_;
  bf16_t* out = features + (size_t)p*CIN_;
  #pragma unroll
  for (int c = lane; c < DS_; c += 32) out[c] = (bf16_t)fs[c];
  #pragma unroll
  for (int c = lane; c < DT_; c += 32)
    out[DS_ + c] = (bf16_t)(w0*f0[c] + w1*f1[c] + w2*f2[c]);
}

// ---------------- GEMM1: x0[M][256] = features[M][384] @ w0^T + b0 (bf16 MFMA) ----------------
__global__ __launch_bounds__(256) void k_gemm1(const bf16_t* __restrict__ A,
                                               const bf16_t* __restrict__ Bw,
                                               const float* __restrict__ bias,
                                               bf16_t* __restrict__ X0,
                                               float* __restrict__ psum, float* __restrict__ psq) {
  __shared__ __align__(16) bf16_t As[128*32];
  __shared__ __align__(16) bf16_t Bs[128*32];
  __shared__ float lsA[256*4], lqA[256*4];
  const int tid = threadIdx.x, w = tid >> 6, l = tid & 63;
  const int bx = blockIdx.x, by = blockIdx.y;
  const int m0 = bx*128, n0 = by*128;
  const int wr = w >> 1, wc = w & 1, l15 = l & 15, l4 = l >> 4;
  f32x4 acc[4][4];
  #pragma unroll
  for (int i = 0; i < 4; ++i)
    #pragma unroll
    for (int j = 0; j < 4; ++j) acc[i][j] = (f32x4){0.f,0.f,0.f,0.f};

  for (int step = 0; step < CIN_/32; ++step) {
    const int k0 = step*32;
    #pragma unroll
    for (int i = 0; i < 2; ++i) {           // wave w stages rows [w*32, w*32+32)
      int row = w*32 + i*16 + (l >> 2);
      int ke  = k0 + (l & 3)*8;
      gl_lds16(A  + (size_t)(m0+row)*CIN_ + ke, &As[row*32 + (l&3)*8]);
      gl_lds16(Bw + (size_t)(n0+row)*CIN_ + ke, &Bs[row*32 + (l&3)*8]);
    }
    asm volatile("s_waitcnt vmcnt(0)" ::: "memory");
    __syncthreads();
    bf16x8 af[4], bfr[4];
    #pragma unroll
    for (int mi = 0; mi < 4; ++mi) af[mi]  = *(const bf16x8*)&As[(wr*64 + mi*16 + l15)*32 + l4*8];
    #pragma unroll
    for (int ni = 0; ni < 4; ++ni) bfr[ni] = *(const bf16x8*)&Bs[(wc*64 + ni*16 + l15)*32 + l4*8];
    #pragma unroll
    for (int mi = 0; mi < 4; ++mi)
      #pragma unroll
      for (int ni = 0; ni < 4; ++ni)
        acc[mi][ni] = __builtin_amdgcn_mfma_f32_16x16x32_bf16(af[mi], bfr[ni], acc[mi][ni], 0, 0, 0);
    __syncthreads();
  }

  float ls[4] = {0,0,0,0}, lq[4] = {0,0,0,0};
  #pragma unroll
  for (int ni = 0; ni < 4; ++ni) {
    int col = n0 + wc*64 + ni*16 + l15;
    float bcol = bias[col];
    #pragma unroll
    for (int mi = 0; mi < 4; ++mi) {
      int rbase = m0 + wr*64 + mi*16 + l4*4;
      #pragma unroll
      for (int r = 0; r < 4; ++r) {
        float v = acc[mi][ni][r] + bcol;
        X0[(size_t)(rbase + r)*C0_ + col] = (bf16_t)v;
        ls[ni] += v; lq[ni] += v*v;
      }
    }
  }
  #pragma unroll
  for (int ni = 0; ni < 4; ++ni) { lsA[tid*4+ni] = ls[ni]; lqA[tid*4+ni] = lq[ni]; }
  __syncthreads();
  if (tid < 128) {                            // deterministic per-column block reduce
    int c = tid, wcc = c >> 6, nii = (c >> 4) & 3, ll = c & 15;
    float s = 0.f, q = 0.f;
    #pragma unroll
    for (int wrr = 0; wrr < 2; ++wrr)
      #pragma unroll
      for (int g4 = 0; g4 < 4; ++g4) {
        int t = (wrr*2 + wcc)*64 + g4*16 + ll;
        s += lsA[t*4 + nii]; q += lqA[t*4 + nii];
      }
    int pb = (bx*2 + by)*128 + c;
    psum[pb] = s; psq[pb] = q;
  }
}

// ---------------- BN0 stats finalize -> scale/shift ----------------
__global__ void k_fin0(const float* __restrict__ psum, const float* __restrict__ psq,
                       const float* __restrict__ gamma, const float* __restrict__ beta,
                       float* __restrict__ scale, float* __restrict__ shift) {
  int c = threadIdx.x;                        // 256
  int nt = c >> 7, cl = c & 127;
  float s = 0.f, q = 0.f;
  for (int mt = 0; mt < 256; ++mt) { int ix = (mt*2 + nt)*128 + cl; s += psum[ix]; q += psq[ix]; }
  float mean = s / (float)M_;
  float var  = q / (float)M_ - mean*mean;
  float sc = gamma[c] * rsqrtf(var + 1e-5f);
  scale[c] = sc; shift[c] = beta[c] - mean*sc;
}

// ---------------- GEMM2: x1[M][128] = relu(BN0(x0)) @ w1^T + b1 ----------------
__global__ __launch_bounds__(256) void k_gemm2(const bf16_t* __restrict__ X0,
                                               const bf16_t* __restrict__ Bw,
                                               const float* __restrict__ scale,
                                               const float* __restrict__ shift,
                                               const float* __restrict__ bias,
                                               bf16_t* __restrict__ X1,
                                               float* __restrict__ psum, float* __restrict__ psq) {
  __shared__ __align__(16) bf16_t As[128*32];
  __shared__ __align__(16) bf16_t Bs[128*32];
  __shared__ float scl[C0_], shl[C0_];
  __shared__ float lsA[256*4], lqA[256*4];
  const int tid = threadIdx.x, w = tid >> 6, l = tid & 63;
  const int m0 = blockIdx.x * 128;
  const int wr = w >> 1, wc = w & 1, l15 = l & 15, l4 = l >> 4;
  scl[tid] = scale[tid]; shl[tid] = shift[tid];   // 256 threads cover C0_
  f32x4 acc[4][4];
  #pragma unroll
  for (int i = 0; i < 4; ++i)
    #pragma unroll
    for (int j = 0; j < 4; ++j) acc[i][j] = (f32x4){0.f,0.f,0.f,0.f};
  __syncthreads();

  for (int step = 0; step < C0_/32; ++step) {
    const int k0 = step*32;
    #pragma unroll
    for (int i = 0; i < 2; ++i) {            // B via async global->LDS
      int row = w*32 + i*16 + (l >> 2);
      gl_lds16(Bw + (size_t)row*C0_ + k0 + (l&3)*8, &Bs[row*32 + (l&3)*8]);
    }
    #pragma unroll
    for (int i = 0; i < 2; ++i) {            // A reg-staged with BN0+ReLU fused
      int ci = i*256 + tid;                  // 0..511
      int row = ci >> 2, ke = (ci & 3)*8;
      bf16x8 v = *(const bf16x8*)(X0 + (size_t)(m0+row)*C0_ + k0 + ke);
      bf16x8 o;
      #pragma unroll
      for (int j = 0; j < 8; ++j) {
        int k = k0 + ke + j;
        float f = fmaxf(fmaf((float)v[j], scl[k], shl[k]), 0.f);
        o[j] = (bf16_t)f;
      }
      *(bf16x8*)&As[row*32 + ke] = o;
    }
    asm volatile("s_waitcnt vmcnt(0)" ::: "memory");
    __syncthreads();
    bf16x8 af[4], bfr[4];
    #pragma unroll
    for (int mi = 0; mi < 4; ++mi) af[mi]  = *(const bf16x8*)&As[(wr*64 + mi*16 + l15)*32 + l4*8];
    #pragma unroll
    for (int ni = 0; ni < 4; ++ni) bfr[ni] = *(const bf16x8*)&Bs[(wc*64 + ni*16 + l15)*32 + l4*8];
    #pragma unroll
    for (int mi = 0; mi < 4; ++mi)
      #pragma unroll
      for (int ni = 0; ni < 4; ++ni)
        acc[mi][ni] = __builtin_amdgcn_mfma_f32_16x16x32_bf16(af[mi], bfr[ni], acc[mi][ni], 0, 0, 0);
    __syncthreads();
  }

  float ls[4] = {0,0,0,0}, lq[4] = {0,0,0,0};
  #pragma unroll
  for (int ni = 0; ni < 4; ++ni) {
    int col = wc*64 + ni*16 + l15;
    float bcol = bias[col];
    #pragma unroll
    for (int mi = 0; mi < 4; ++mi) {
      int rbase = m0 + wr*64 + mi*16 + l4*4;
      #pragma unroll
      for (int r = 0; r < 4; ++r) {
        float v = acc[mi][ni][r] + bcol;
        X1[(size_t)(rbase + r)*C1_ + col] = (bf16_t)v;
        ls[ni] += v; lq[ni] += v*v;
      }
    }
  }
  #pragma unroll
  for (int ni = 0; ni < 4; ++ni) { lsA[tid*4+ni] = ls[ni]; lqA[tid*4+ni] = lq[ni]; }
  __syncthreads();
  if (tid < 128) {
    int c = tid, wcc = c >> 6, nii = (c >> 4) & 3, ll = c & 15;
    float s = 0.f, q = 0.f;
    #pragma unroll
    for (int wrr = 0; wrr < 2; ++wrr)
      #pragma unroll
      for (int g4 = 0; g4 < 4; ++g4) {
        int t = (wrr*2 + wcc)*64 + g4*16 + ll;
        s += lsA[t*4 + nii]; q += lqA[t*4 + nii];
      }
    psum[blockIdx.x*128 + c] = s; psq[blockIdx.x*128 + c] = q;
  }
}

// ---------------- BN1 stats finalize ----------------
__global__ void k_fin1(const float* __restrict__ psum, const float* __restrict__ psq,
                       const float* __restrict__ gamma, const float* __restrict__ beta,
                       float* __restrict__ scale, float* __restrict__ shift) {
  int c = threadIdx.x;                        // 128
  float s = 0.f, q = 0.f;
  for (int mt = 0; mt < 256; ++mt) { s += psum[mt*128 + c]; q += psq[mt*128 + c]; }
  float mean = s / (float)M_;
  float var  = q / (float)M_ - mean*mean;
  float sc = gamma[c] * rsqrtf(var + 1e-5f);
  scale[c] = sc; shift[c] = beta[c] - mean*sc;
}

// ---------------- apply BN1 + ReLU -> fp32 output ----------------
__global__ __launch_bounds__(256) void k_apply(const bf16_t* __restrict__ X1,
                                               const float* __restrict__ scale,
                                               const float* __restrict__ shift,
                                               float* __restrict__ out) {
  int t = blockIdx.x * 256 + threadIdx.x;     // 524288 threads * 8 elems
  size_t base = (size_t)t * 8;
  bf16x8 v = *(const bf16x8*)(X1 + base);
  int c0 = (t & 15) * 8;                      // base % 128
  #pragma unroll
  for (int j = 0; j < 8; ++j) {
    float f = fmaf((float)v[j], scale[c0+j], shift[c0+j]);
    out[base + j] = fmaxf(f, 0.f);
  }
}

extern "C" void kernel_launch(void* const* d_in, const int* in_sizes, int n_in,
                              void* d_out, int out_size, void* d_ws, size_t ws_size,
                              hipStream_t stream) {
  (void)in_sizes; (void)n_in; (void)out_size; (void)ws_size;
  const float* xyz_s   = (const float*)d_in[0];
  const float* xyz_t   = (const float*)d_in[1];
  const float* feats_s = (const float*)d_in[2];
  const float* feats_t = (const float*)d_in[3];
  const float* w0      = (const float*)d_in[4];
  const float* b0      = (const float*)d_in[5];
  const float* gamma0  = (const float*)d_in[6];
  const float* beta0   = (const float*)d_in[7];
  const float* w1      = (const float*)d_in[8];
  const float* b1      = (const float*)d_in[9];
  const float* gamma1  = (const float*)d_in[10];
  const float* beta1   = (const float*)d_in[11];
  float* out = (float*)d_out;

  char* ws = (char*)d_ws;
  size_t off = 0;
  auto alloc = [&](size_t bytes) -> void* {
    void* p = ws + off;
    off = (off + bytes + 255) & ~(size_t)255;
    return p;
  };
  float*  pd      = (float*) alloc((size_t)M_*NCH_*3*4);
  int*    pi      = (int*)   alloc((size_t)M_*NCH_*3*4);
  float*  wgt     = (float*) alloc((size_t)M_*3*4);
  int*    widx    = (int*)   alloc((size_t)M_*3*4);
  bf16_t* features= (bf16_t*)alloc((size_t)M_*CIN_*2);
  bf16_t* w0b     = (bf16_t*)alloc((size_t)C0_*CIN_*2);
  bf16_t* w1b     = (bf16_t*)alloc((size_t)C1_*C0_*2);
  bf16_t* x0      = (bf16_t*)alloc((size_t)M_*C0_*2);
  float*  psum0   = (float*) alloc(512*128*4);
  float*  psq0    = (float*) alloc(512*128*4);
  float*  scale0  = (float*) alloc(256*4);
  float*  shift0  = (float*) alloc(256*4);
  float*  psum1   = (float*) alloc(256*128*4);
  float*  psq1    = (float*) alloc(256*128*4);
  float*  scale1  = (float*) alloc(128*4);
  float*  shift1  = (float*) alloc(128*4);
  bf16_t* x1      = features;                 // features dead after gemm1 -> reuse

  k_convw <<<dim3(384), dim3(256), 0, stream>>>(w0, w1, w0b, w1b);
  k_knn   <<<dim3(N_/256, NCH_, B_), dim3(256), 0, stream>>>(xyz_s, xyz_t, pd, pi);
  k_merge <<<dim3(M_/256), dim3(256), 0, stream>>>(pd, pi, wgt, widx);
  k_gather<<<dim3(M_/8), dim3(256), 0, stream>>>(feats_s, feats_t, wgt, widx, features);
  k_gemm1 <<<dim3(M_/128, C0_/128), dim3(256), 0, stream>>>(features, w0b, b0, x0, psum0, psq0);
  k_fin0  <<<dim3(1), dim3(256), 0, stream>>>(psum0, psq0, gamma0, beta0, scale0, shift0);
  k_gemm2 <<<dim3(M_/128), dim3(256), 0, stream>>>(x0, w1b, scale0, shift0, b1, x1, psum1, psq1);
  k_fin1  <<<dim3(1), dim3(128), 0, stream>>>(psum1, psq1, gamma1, beta1, scale1, shift1);
  k_apply <<<dim3(M_*C1_/8/256), dim3(256), 0, stream>>>(x1, scale1, shift1, out);
}

// Round 2
// 164.090 us; speedup vs baseline: 1.9446x; 1.9446x over previous
//
#include <hip/hip_runtime.h>
#include <hip/hip_bf16.h>

typedef __bf16 bf16_t;
typedef __bf16 bf16x8 __attribute__((ext_vector_type(8)));
typedef float f32x4 __attribute__((ext_vector_type(4)));

#define B_   2
#define N_   16384
#define S_   4096
#define DS_  128
#define DT_  256
#define CIN_ 384
#define C0_  256
#define C1_  128
#define M_   (B_*N_)      // 32768 points total
#define NCH_ 16
#define SCH_ (S_/NCH_)    // 256 targets per chunk

__device__ __forceinline__ void gl_lds16(const void* g, void* l) {
  __builtin_amdgcn_global_load_lds((const __attribute__((address_space(1))) void*)g,
                                   (__attribute__((address_space(3))) void*)l, 16, 0, 0);
}

// branchy top-3 insert with exact lexicographic (d, idx) strict-less (used in small merges)
__device__ __forceinline__ void lins3(float d, int ix,
                                      float& d0, float& d1, float& d2,
                                      int& i0, int& i1, int& i2) {
  if (d < d2 || (d == d2 && ix < i2)) {
    d2 = d; i2 = ix;
    if (d2 < d1 || (d2 == d1 && i2 < i1)) {
      float td = d1; d1 = d2; d2 = td; int ti = i1; i1 = i2; i2 = ti;
      if (d1 < d0 || (d1 == d0 && i1 < i0)) {
        td = d0; d0 = d1; d1 = td; ti = i0; i0 = i1; i1 = ti;
      }
    }
  }
}

// plain strict-< insert (candidates arrive in ascending-index order => stable)
__device__ __forceinline__ void ins3(float d, int ix,
                                     float& d0, float& d1, float& d2,
                                     int& i0, int& i1, int& i2) {
  if (d < d2) {
    if (d < d1) {
      d2 = d1; i2 = i1;
      if (d < d0) { d1 = d0; i1 = i0; d0 = d; i0 = ix; }
      else        { d1 = d;  i1 = ix; }
    } else { d2 = d; i2 = ix; }
  }
}

// ---------------- weights fp32 -> bf16 ----------------
__global__ void k_convw(const float* __restrict__ w0, const float* __restrict__ w1,
                        bf16_t* __restrict__ w0b, bf16_t* __restrict__ w1b) {
  int i = blockIdx.x * 256 + threadIdx.x;
  if (i < C0_*CIN_) w0b[i] = (bf16_t)w0[i];
  if (i < C1_*C0_)  w1b[i] = (bf16_t)w1[i];
}

// ---------------- 3-NN over one target chunk ----------------
// Exact numpy fp32 order: d = (s2 + t2) - 2*((sx tx + sy ty) + sz tz)
// 4 independent branchless top-3 chains (stride-4 target assignment) for ILP,
// merged in-thread with exact lexicographic comparator.
__global__ __launch_bounds__(256, 8) void k_knn(const float* __restrict__ xyz_s,
                                                const float* __restrict__ xyz_t,
                                                float* __restrict__ pd, int* __restrict__ pi) {
  __shared__ float4 tgt[SCH_];
  const int b = blockIdx.z, ch = blockIdx.y;
  const int n = blockIdx.x * 256 + threadIdx.x;
  const int s0 = ch * SCH_;
  {
    int j = threadIdx.x;                       // 256 threads cover SCH_=256
    const float* q = xyz_t + ((size_t)b*S_ + s0 + j)*3;
    float x = q[0], y = q[1], z = q[2];
    float t2 = __fadd_rn(__fadd_rn(__fmul_rn(x,x), __fmul_rn(y,y)), __fmul_rn(z,z));
    tgt[j] = make_float4(x, y, z, t2);
  }
  __syncthreads();
  const float* ps = xyz_s + ((size_t)b*N_ + n)*3;
  const float sx = ps[0], sy = ps[1], sz = ps[2];
  const float s2 = __fadd_rn(__fadd_rn(__fmul_rn(sx,sx), __fmul_rn(sy,sy)), __fmul_rn(sz,sz));

  float D0[4], D1[4], D2[4];
  int   I0[4], I1[4], I2[4];
  #pragma unroll
  for (int c = 0; c < 4; ++c) { D0[c]=D1[c]=D2[c]=3.4e38f; I0[c]=I1[c]=I2[c]=0; }

  #pragma unroll 2
  for (int t = 0; t < SCH_/4; ++t) {
    #pragma unroll
    for (int c = 0; c < 4; ++c) {
      const int j = t*4 + c;
      float4 tg = tgt[j];
      float dot = __fadd_rn(__fadd_rn(__fmul_rn(sx,tg.x), __fmul_rn(sy,tg.y)), __fmul_rn(sz,tg.z));
      float d   = __fsub_rn(__fadd_rn(s2, tg.w), __fmul_rn(2.f, dot));
      // branchless insert (strict <, candidates ascending j => stable ties)
      bool c2 = d < D2[c];
      D2[c] = c2 ? d : D2[c];
      I2[c] = c2 ? j : I2[c];
      bool c1 = D2[c] < D1[c];
      float mn1 = fminf(D1[c], D2[c]), mx1 = fmaxf(D1[c], D2[c]);
      int   a1  = c1 ? I2[c] : I1[c],  a2 = c1 ? I1[c] : I2[c];
      D1[c] = mn1; D2[c] = mx1; I1[c] = a1; I2[c] = a2;
      bool c0 = D1[c] < D0[c];
      float mn0 = fminf(D0[c], D1[c]), mx0 = fmaxf(D0[c], D1[c]);
      int   b0  = c0 ? I1[c] : I0[c],  b1 = c0 ? I0[c] : I1[c];
      D0[c] = mn0; D1[c] = mx0; I0[c] = b0; I1[c] = b1;
    }
  }

  // merge 4 chains (12 candidates) with exact lexicographic comparator
  float e0 = D0[0], e1 = D1[0], e2 = D2[0];
  int   x0 = I0[0], x1 = I1[0], x2 = I2[0];
  #pragma unroll
  for (int c = 1; c < 4; ++c) {
    lins3(D0[c], I0[c], e0, e1, e2, x0, x1, x2);
    lins3(D1[c], I1[c], e0, e1, e2, x0, x1, x2);
    lins3(D2[c], I2[c], e0, e1, e2, x0, x1, x2);
  }

  size_t base = ((size_t)(b*N_ + n)*NCH_ + ch)*3;
  pd[base+0] = e0; pd[base+1] = e1; pd[base+2] = e2;
  pi[base+0] = s0+x0; pi[base+1] = s0+x1; pi[base+2] = s0+x2;
}

// ---------------- merge chunk candidates, compute inverse-distance weights ----------------
__global__ void k_merge(const float* __restrict__ pd, const int* __restrict__ pi,
                        float* __restrict__ wgt, int* __restrict__ widx) {
  int p = blockIdx.x * 256 + threadIdx.x;  // 0..32767
  float d0 = 3.4e38f, d1 = 3.4e38f, d2 = 3.4e38f;
  int   i0 = 0, i1 = 0, i2 = 0;
  size_t base = (size_t)p * (NCH_*3);
  #pragma unroll 4
  for (int c = 0; c < NCH_*3; ++c)        // chunk-major = ascending target index
    ins3(pd[base+c], pi[base+c], d0, d1, d2, i0, i1, i2);
  float r0 = 1.f/(d0 + 1e-8f), r1 = 1.f/(d1 + 1e-8f), r2 = 1.f/(d2 + 1e-8f);
  float s = r0 + r1 + r2;
  wgt[p*3+0] = r0/s; wgt[p*3+1] = r1/s; wgt[p*3+2] = r2/s;
  widx[p*3+0] = i0;  widx[p*3+1] = i1;  widx[p*3+2] = i2;
}

// ---------------- gather + interpolate + concat -> features (bf16, [M][384]) ----------------
__global__ __launch_bounds__(256) void k_gather(const float* __restrict__ feats_s,
                                                const float* __restrict__ feats_t,
                                                const float* __restrict__ wgt,
                                                const int* __restrict__ widx,
                                                bf16_t* __restrict__ features) {
  const int g = threadIdx.x >> 5, lane = threadIdx.x & 31;
  const int p = blockIdx.x * 8 + g;
  const int b = p >> 14;                       // N_ = 2^14
  const float w0 = wgt[p*3+0], w1 = wgt[p*3+1], w2 = wgt[p*3+2];
  const int   j0 = widx[p*3+0], j1 = widx[p*3+1], j2 = widx[p*3+2];
  const float* f0 = feats_t + ((size_t)b*S_ + j0)*DT_;
  const float* f1 = feats_t + ((size_t)b*S_ + j1)*DT_;
  const float* f2 = feats_t + ((size_t)b*S_ + j2)*DT_;
  const float* fs = feats_s + (size_t)p*DS_;
  bf16_t* out = features + (size_t)p*CIN_;
  #pragma unroll
  for (int c = lane; c < DS_; c += 32) out[c] = (bf16_t)fs[c];
  #pragma unroll
  for (int c = lane; c < DT_; c += 32)
    out[DS_ + c] = (bf16_t)(w0*f0[c] + w1*f1[c] + w2*f2[c]);
}

// ---------------- GEMM1: x0[M][256] = features[M][384] @ w0^T + b0 (bf16 MFMA) ----------------
__global__ __launch_bounds__(256) void k_gemm1(const bf16_t* __restrict__ A,
                                               const bf16_t* __restrict__ Bw,
                                               const float* __restrict__ bias,
                                               bf16_t* __restrict__ X0,
                                               float* __restrict__ psum, float* __restrict__ psq) {
  __shared__ __align__(16) bf16_t As[128*32];
  __shared__ __align__(16) bf16_t Bs[128*32];
  __shared__ float lsA[256*4], lqA[256*4];
  const int tid = threadIdx.x, w = tid >> 6, l = tid & 63;
  const int bx = blockIdx.x, by = blockIdx.y;
  const int m0 = bx*128, n0 = by*128;
  const int wr = w >> 1, wc = w & 1, l15 = l & 15, l4 = l >> 4;
  f32x4 acc[4][4];
  #pragma unroll
  for (int i = 0; i < 4; ++i)
    #pragma unroll
    for (int j = 0; j < 4; ++j) acc[i][j] = (f32x4){0.f,0.f,0.f,0.f};

  for (int step = 0; step < CIN_/32; ++step) {
    const int k0 = step*32;
    #pragma unroll
    for (int i = 0; i < 2; ++i) {
      int row = w*32 + i*16 + (l >> 2);
      int ke  = k0 + (l & 3)*8;
      gl_lds16(A  + (size_t)(m0+row)*CIN_ + ke, &As[row*32 + (l&3)*8]);
      gl_lds16(Bw + (size_t)(n0+row)*CIN_ + ke, &Bs[row*32 + (l&3)*8]);
    }
    asm volatile("s_waitcnt vmcnt(0)" ::: "memory");
    __syncthreads();
    bf16x8 af[4], bfr[4];
    #pragma unroll
    for (int mi = 0; mi < 4; ++mi) af[mi]  = *(const bf16x8*)&As[(wr*64 + mi*16 + l15)*32 + l4*8];
    #pragma unroll
    for (int ni = 0; ni < 4; ++ni) bfr[ni] = *(const bf16x8*)&Bs[(wc*64 + ni*16 + l15)*32 + l4*8];
    #pragma unroll
    for (int mi = 0; mi < 4; ++mi)
      #pragma unroll
      for (int ni = 0; ni < 4; ++ni)
        acc[mi][ni] = __builtin_amdgcn_mfma_f32_16x16x32_bf16(af[mi], bfr[ni], acc[mi][ni], 0, 0, 0);
    __syncthreads();
  }

  float ls[4] = {0,0,0,0}, lq[4] = {0,0,0,0};
  #pragma unroll
  for (int ni = 0; ni < 4; ++ni) {
    int col = n0 + wc*64 + ni*16 + l15;
    float bcol = bias[col];
    #pragma unroll
    for (int mi = 0; mi < 4; ++mi) {
      int rbase = m0 + wr*64 + mi*16 + l4*4;
      #pragma unroll
      for (int r = 0; r < 4; ++r) {
        float v = acc[mi][ni][r] + bcol;
        X0[(size_t)(rbase + r)*C0_ + col] = (bf16_t)v;
        ls[ni] += v; lq[ni] += v*v;
      }
    }
  }
  #pragma unroll
  for (int ni = 0; ni < 4; ++ni) { lsA[tid*4+ni] = ls[ni]; lqA[tid*4+ni] = lq[ni]; }
  __syncthreads();
  if (tid < 128) {
    int c = tid, wcc = c >> 6, nii = (c >> 4) & 3, ll = c & 15;
    float s = 0.f, q = 0.f;
    #pragma unroll
    for (int wrr = 0; wrr < 2; ++wrr)
      #pragma unroll
      for (int g4 = 0; g4 < 4; ++g4) {
        int t = (wrr*2 + wcc)*64 + g4*16 + ll;
        s += lsA[t*4 + nii]; q += lqA[t*4 + nii];
      }
    int pb = (bx*2 + by)*128 + c;
    psum[pb] = s; psq[pb] = q;
  }
}

// ---------------- BN0 stats finalize: one block per channel ----------------
__global__ __launch_bounds__(256) void k_fin0(const float* __restrict__ psum, const float* __restrict__ psq,
                       const float* __restrict__ gamma, const float* __restrict__ beta,
                       float* __restrict__ scale, float* __restrict__ shift) {
  __shared__ float sw[4], qw[4];
  int c = blockIdx.x, t = threadIdx.x;       // 256 blocks, 256 threads
  int nt = c >> 7, cl = c & 127;
  int ix = (t*2 + nt)*128 + cl;              // m-tile t, n-tile nt
  float s = psum[ix], q = psq[ix];
  #pragma unroll
  for (int o = 32; o; o >>= 1) { s += __shfl_down(s, o, 64); q += __shfl_down(q, o, 64); }
  if ((t & 63) == 0) { sw[t>>6] = s; qw[t>>6] = q; }
  __syncthreads();
  if (t == 0) {
    s = (sw[0]+sw[1])+(sw[2]+sw[3]); q = (qw[0]+qw[1])+(qw[2]+qw[3]);
    float mean = s / (float)M_;
    float var  = q / (float)M_ - mean*mean;
    float sc = gamma[c] * rsqrtf(var + 1e-5f);
    scale[c] = sc; shift[c] = beta[c] - mean*sc;
  }
}

// ---------------- GEMM2: x1[M][128] = relu(BN0(x0)) @ w1^T + b1 ----------------
__global__ __launch_bounds__(256) void k_gemm2(const bf16_t* __restrict__ X0,
                                               const bf16_t* __restrict__ Bw,
                                               const float* __restrict__ scale,
                                               const float* __restrict__ shift,
                                               const float* __restrict__ bias,
                                               bf16_t* __restrict__ X1,
                                               float* __restrict__ psum, float* __restrict__ psq) {
  __shared__ __align__(16) bf16_t As[128*32];
  __shared__ __align__(16) bf16_t Bs[128*32];
  __shared__ float scl[C0_], shl[C0_];
  __shared__ float lsA[256*4], lqA[256*4];
  const int tid = threadIdx.x, w = tid >> 6, l = tid & 63;
  const int m0 = blockIdx.x * 128;
  const int wr = w >> 1, wc = w & 1, l15 = l & 15, l4 = l >> 4;
  scl[tid] = scale[tid]; shl[tid] = shift[tid];
  f32x4 acc[4][4];
  #pragma unroll
  for (int i = 0; i < 4; ++i)
    #pragma unroll
    for (int j = 0; j < 4; ++j) acc[i][j] = (f32x4){0.f,0.f,0.f,0.f};
  __syncthreads();

  for (int step = 0; step < C0_/32; ++step) {
    const int k0 = step*32;
    #pragma unroll
    for (int i = 0; i < 2; ++i) {
      int row = w*32 + i*16 + (l >> 2);
      gl_lds16(Bw + (size_t)row*C0_ + k0 + (l&3)*8, &Bs[row*32 + (l&3)*8]);
    }
    #pragma unroll
    for (int i = 0; i < 2; ++i) {
      int ci = i*256 + tid;
      int row = ci >> 2, ke = (ci & 3)*8;
      bf16x8 v = *(const bf16x8*)(X0 + (size_t)(m0+row)*C0_ + k0 + ke);
      bf16x8 o;
      #pragma unroll
      for (int j = 0; j < 8; ++j) {
        int k = k0 + ke + j;
        float f = fmaxf(fmaf((float)v[j], scl[k], shl[k]), 0.f);
        o[j] = (bf16_t)f;
      }
      *(bf16x8*)&As[row*32 + ke] = o;
    }
    asm volatile("s_waitcnt vmcnt(0)" ::: "memory");
    __syncthreads();
    bf16x8 af[4], bfr[4];
    #pragma unroll
    for (int mi = 0; mi < 4; ++mi) af[mi]  = *(const bf16x8*)&As[(wr*64 + mi*16 + l15)*32 + l4*8];
    #pragma unroll
    for (int ni = 0; ni < 4; ++ni) bfr[ni] = *(const bf16x8*)&Bs[(wc*64 + ni*16 + l15)*32 + l4*8];
    #pragma unroll
    for (int mi = 0; mi < 4; ++mi)
      #pragma unroll
      for (int ni = 0; ni < 4; ++ni)
        acc[mi][ni] = __builtin_amdgcn_mfma_f32_16x16x32_bf16(af[mi], bfr[ni], acc[mi][ni], 0, 0, 0);
    __syncthreads();
  }

  float ls[4] = {0,0,0,0}, lq[4] = {0,0,0,0};
  #pragma unroll
  for (int ni = 0; ni < 4; ++ni) {
    int col = wc*64 + ni*16 + l15;
    float bcol = bias[col];
    #pragma unroll
    for (int mi = 0; mi < 4; ++mi) {
      int rbase = m0 + wr*64 + mi*16 + l4*4;
      #pragma unroll
      for (int r = 0; r < 4; ++r) {
        float v = acc[mi][ni][r] + bcol;
        X1[(size_t)(rbase + r)*C1_ + col] = (bf16_t)v;
        ls[ni] += v; lq[ni] += v*v;
      }
    }
  }
  #pragma unroll
  for (int ni = 0; ni < 4; ++ni) { lsA[tid*4+ni] = ls[ni]; lqA[tid*4+ni] = lq[ni]; }
  __syncthreads();
  if (tid < 128) {
    int c = tid, wcc = c >> 6, nii = (c >> 4) & 3, ll = c & 15;
    float s = 0.f, q = 0.f;
    #pragma unroll
    for (int wrr = 0; wrr < 2; ++wrr)
      #pragma unroll
      for (int g4 = 0; g4 < 4; ++g4) {
        int t = (wrr*2 + wcc)*64 + g4*16 + ll;
        s += lsA[t*4 + nii]; q += lqA[t*4 + nii];
      }
    psum[blockIdx.x*128 + c] = s; psq[blockIdx.x*128 + c] = q;
  }
}

// ---------------- BN1 stats finalize: one block per channel ----------------
__global__ __launch_bounds__(256) void k_fin1(const float* __restrict__ psum, const float* __restrict__ psq,
                       const float* __restrict__ gamma, const float* __restrict__ beta,
                       float* __restrict__ scale, float* __restrict__ shift) {
  __shared__ float sw[4], qw[4];
  int c = blockIdx.x, t = threadIdx.x;       // 128 blocks, 256 threads
  int ix = t*128 + c;
  float s = psum[ix], q = psq[ix];
  #pragma unroll
  for (int o = 32; o; o >>= 1) { s += __shfl_down(s, o, 64); q += __shfl_down(q, o, 64); }
  if ((t & 63) == 0) { sw[t>>6] = s; qw[t>>6] = q; }
  __syncthreads();
  if (t == 0) {
    s = (sw[0]+sw[1])+(sw[2]+sw[3]); q = (qw[0]+qw[1])+(qw[2]+qw[3]);
    float mean = s / (float)M_;
    float var  = q / (float)M_ - mean*mean;
    float sc = gamma[c] * rsqrtf(var + 1e-5f);
    scale[c] = sc; shift[c] = beta[c] - mean*sc;
  }
}

// ---------------- apply BN1 + ReLU -> fp32 output ----------------
__global__ __launch_bounds__(256) void k_apply(const bf16_t* __restrict__ X1,
                                               const float* __restrict__ scale,
                                               const float* __restrict__ shift,
                                               float* __restrict__ out) {
  int t = blockIdx.x * 256 + threadIdx.x;
  size_t base = (size_t)t * 8;
  bf16x8 v = *(const bf16x8*)(X1 + base);
  int c0 = (t & 15) * 8;
  #pragma unroll
  for (int j = 0; j < 8; ++j) {
    float f = fmaf((float)v[j], scale[c0+j], shift[c0+j]);
    out[base + j] = fmaxf(f, 0.f);
  }
}

extern "C" void kernel_launch(void* const* d_in, const int* in_sizes, int n_in,
                              void* d_out, int out_size, void* d_ws, size_t ws_size,
                              hipStream_t stream) {
  (void)in_sizes; (void)n_in; (void)out_size; (void)ws_size;
  const float* xyz_s   = (const float*)d_in[0];
  const float* xyz_t   = (const float*)d_in[1];
  const float* feats_s = (const float*)d_in[2];
  const float* feats_t = (const float*)d_in[3];
  const float* w0      = (const float*)d_in[4];
  const float* b0      = (const float*)d_in[5];
  const float* gamma0  = (const float*)d_in[6];
  const float* beta0   = (const float*)d_in[7];
  const float* w1      = (const float*)d_in[8];
  const float* b1      = (const float*)d_in[9];
  const float* gamma1  = (const float*)d_in[10];
  const float* beta1   = (const float*)d_in[11];
  float* out = (float*)d_out;

  char* ws = (char*)d_ws;
  size_t off = 0;
  auto alloc = [&](size_t bytes) -> void* {
    void* p = ws + off;
    off = (off + bytes + 255) & ~(size_t)255;
    return p;
  };
  float*  wgt     = (float*) alloc((size_t)M_*3*4);
  int*    widx    = (int*)   alloc((size_t)M_*3*4);
  // union region: {pd, pi} (dead after k_merge)  overlaid by  {features/x1}
  char*   uni     = (char*)  alloc((size_t)M_*CIN_*2);     // 25.2 MB >= pd+pi (12.6 MB)
  float*  pd      = (float*) uni;
  int*    pi      = (int*)  (uni + (size_t)M_*NCH_*3*4);
  bf16_t* features= (bf16_t*)uni;
  bf16_t* w0b     = (bf16_t*)alloc((size_t)C0_*CIN_*2);
  bf16_t* w1b     = (bf16_t*)alloc((size_t)C1_*C0_*2);
  bf16_t* x0      = (bf16_t*)alloc((size_t)M_*C0_*2);
  float*  psum0   = (float*) alloc(512*128*4);
  float*  psq0    = (float*) alloc(512*128*4);
  float*  scale0  = (float*) alloc(256*4);
  float*  shift0  = (float*) alloc(256*4);
  float*  psum1   = (float*) alloc(256*128*4);
  float*  psq1    = (float*) alloc(256*128*4);
  float*  scale1  = (float*) alloc(128*4);
  float*  shift1  = (float*) alloc(128*4);
  bf16_t* x1      = features;                 // features dead after gemm1 -> reuse

  k_convw <<<dim3(384), dim3(256), 0, stream>>>(w0, w1, w0b, w1b);
  k_knn   <<<dim3(N_/256, NCH_, B_), dim3(256), 0, stream>>>(xyz_s, xyz_t, pd, pi);
  k_merge <<<dim3(M_/256), dim3(256), 0, stream>>>(pd, pi, wgt, widx);
  k_gather<<<dim3(M_/8), dim3(256), 0, stream>>>(feats_s, feats_t, wgt, widx, features);
  k_gemm1 <<<dim3(M_/128, C0_/128), dim3(256), 0, stream>>>(features, w0b, b0, x0, psum0, psq0);
  k_fin0  <<<dim3(256), dim3(256), 0, stream>>>(psum0, psq0, gamma0, beta0, scale0, shift0);
  k_gemm2 <<<dim3(M_/128), dim3(256), 0, stream>>>(x0, w1b, scale0, shift0, b1, x1, psum1, psq1);
  k_fin1  <<<dim3(128), dim3(256), 0, stream>>>(psum1, psq1, gamma1, beta1, scale1, shift1);
  k_apply <<<dim3(M_*C1_/8/256), dim3(256), 0, stream>>>(x1, scale1, shift1, out);
}

// Round 3
// 153.541 us; speedup vs baseline: 2.0782x; 1.0687x over previous
//
#include <hip/hip_runtime.h>
#include <hip/hip_bf16.h>

typedef __bf16 bf16_t;
typedef __bf16 bf16x8 __attribute__((ext_vector_type(8)));
typedef float f32x4 __attribute__((ext_vector_type(4)));

#define B_   2
#define N_   16384
#define S_   4096
#define DS_  128
#define DT_  256
#define CIN_ 384
#define C0_  256
#define C1_  128
#define M_   (B_*N_)      // 32768 points total
#define NCH_ 16
#define SCH_ (S_/NCH_)    // 256 targets per chunk

__device__ __forceinline__ void gl_lds16(const void* g, void* l) {
  __builtin_amdgcn_global_load_lds((const __attribute__((address_space(1))) void*)g,
                                   (__attribute__((address_space(3))) void*)l, 16, 0, 0);
}

// branchy top-3 insert with exact lexicographic (d, idx) strict-less (small merges only)
__device__ __forceinline__ void lins3(float d, int ix,
                                      float& d0, float& d1, float& d2,
                                      int& i0, int& i1, int& i2) {
  if (d < d2 || (d == d2 && ix < i2)) {
    d2 = d; i2 = ix;
    if (d2 < d1 || (d2 == d1 && i2 < i1)) {
      float td = d1; d1 = d2; d2 = td; int ti = i1; i1 = i2; i2 = ti;
      if (d1 < d0 || (d1 == d0 && i1 < i0)) {
        td = d0; d0 = d1; d1 = td; ti = i0; i0 = i1; i1 = ti;
      }
    }
  }
}

// plain strict-< insert (candidates arrive in ascending-index order => stable)
__device__ __forceinline__ void ins3(float d, int ix,
                                     float& d0, float& d1, float& d2,
                                     int& i0, int& i1, int& i2) {
  if (d < d2) {
    if (d < d1) {
      d2 = d1; i2 = i1;
      if (d < d0) { d1 = d0; i1 = i0; d0 = d; i0 = ix; }
      else        { d1 = d;  i1 = ix; }
    } else { d2 = d; i2 = ix; }
  }
}

// ---------------- weights fp32 -> bf16 ----------------
__global__ void k_convw(const float* __restrict__ w0, const float* __restrict__ w1,
                        bf16_t* __restrict__ w0b, bf16_t* __restrict__ w1b) {
  int i = blockIdx.x * 256 + threadIdx.x;
  if (i < C0_*CIN_) w0b[i] = (bf16_t)w0[i];
  if (i < C1_*C0_)  w1b[i] = (bf16_t)w1[i];
}

// ---------------- 3-NN over one target chunk ----------------
// Exact numpy fp32 order: d = (s2 + t2) - 2*((sx tx + sy ty) + sz tz)
// 4 independent chains; insert = min/med3/med3 (3 ops) + 3 cmp + 5 cndmask.
__global__ __launch_bounds__(256, 4) void k_knn(const float* __restrict__ xyz_s,
                                                const float* __restrict__ xyz_t,
                                                float* __restrict__ pd, int* __restrict__ pi) {
  __shared__ float4 tgt[SCH_];
  const int b = blockIdx.z, ch = blockIdx.y;
  const int n = blockIdx.x * 256 + threadIdx.x;
  const int s0 = ch * SCH_;
  {
    int j = threadIdx.x;                       // 256 threads cover SCH_=256
    const float* q = xyz_t + ((size_t)b*S_ + s0 + j)*3;
    float x = q[0], y = q[1], z = q[2];
    float t2 = __fadd_rn(__fadd_rn(__fmul_rn(x,x), __fmul_rn(y,y)), __fmul_rn(z,z));
    tgt[j] = make_float4(x, y, z, t2);
  }
  __syncthreads();
  const float* ps = xyz_s + ((size_t)b*N_ + n)*3;
  const float sx = ps[0], sy = ps[1], sz = ps[2];
  const float s2 = __fadd_rn(__fadd_rn(__fmul_rn(sx,sx), __fmul_rn(sy,sy)), __fmul_rn(sz,sz));

  float D0[4], D1[4], D2[4];
  int   I0[4], I1[4], I2[4];
  #pragma unroll
  for (int c = 0; c < 4; ++c) { D0[c]=D1[c]=D2[c]=3.4e38f; I0[c]=I1[c]=I2[c]=0; }

  #pragma unroll 4
  for (int t = 0; t < SCH_/4; ++t) {
    #pragma unroll
    for (int c = 0; c < 4; ++c) {
      const int j = t*4 + c;
      float4 tg = tgt[j];
      float dot = __fadd_rn(__fadd_rn(__fmul_rn(sx,tg.x), __fmul_rn(sy,tg.y)), __fmul_rn(sz,tg.z));
      float d   = __fsub_rn(__fadd_rn(s2, tg.w), __fmul_rn(2.f, dot));
      // --- index updates: all compares against OLD state (CSE-able, strict < => stable)
      int t2i = (d < D1[c]) ? I1[c] : j;
      int nI2 = (d < D2[c]) ? t2i  : I2[c];
      int t1i = (d < D0[c]) ? I0[c] : j;
      int nI1 = (d < D1[c]) ? t1i  : I1[c];
      int nI0 = (d < D0[c]) ? j    : I0[c];
      // --- distance updates: sorted-insert via min/med3/med3 (old values)
      float nD2 = __builtin_amdgcn_fmed3f(D1[c], D2[c], d);
      float nD1 = __builtin_amdgcn_fmed3f(D0[c], D1[c], d);
      float nD0 = fminf(D0[c], d);
      I0[c]=nI0; I1[c]=nI1; I2[c]=nI2;
      D0[c]=nD0; D1[c]=nD1; D2[c]=nD2;
    }
  }

  // merge 4 chains (12 candidates) with exact lexicographic comparator
  float e0 = D0[0], e1 = D1[0], e2 = D2[0];
  int   x0 = I0[0], x1 = I1[0], x2 = I2[0];
  #pragma unroll
  for (int c = 1; c < 4; ++c) {
    lins3(D0[c], I0[c], e0, e1, e2, x0, x1, x2);
    lins3(D1[c], I1[c], e0, e1, e2, x0, x1, x2);
    lins3(D2[c], I2[c], e0, e1, e2, x0, x1, x2);
  }

  size_t base = ((size_t)(b*N_ + n)*NCH_ + ch)*3;
  pd[base+0] = e0; pd[base+1] = e1; pd[base+2] = e2;
  pi[base+0] = s0+x0; pi[base+1] = s0+x1; pi[base+2] = s0+x2;
}

// ---------------- merge chunk candidates, compute inverse-distance weights ----------------
__global__ void k_merge(const float* __restrict__ pd, const int* __restrict__ pi,
                        float* __restrict__ wgt, int* __restrict__ widx) {
  int p = blockIdx.x * 256 + threadIdx.x;  // 0..32767
  float d0 = 3.4e38f, d1 = 3.4e38f, d2 = 3.4e38f;
  int   i0 = 0, i1 = 0, i2 = 0;
  size_t base = (size_t)p * (NCH_*3);
  #pragma unroll 4
  for (int c = 0; c < NCH_*3; ++c)        // chunk-major = ascending target index
    ins3(pd[base+c], pi[base+c], d0, d1, d2, i0, i1, i2);
  float r0 = 1.f/(d0 + 1e-8f), r1 = 1.f/(d1 + 1e-8f), r2 = 1.f/(d2 + 1e-8f);
  float s = r0 + r1 + r2;
  wgt[p*3+0] = r0/s; wgt[p*3+1] = r1/s; wgt[p*3+2] = r2/s;
  widx[p*3+0] = i0;  widx[p*3+1] = i1;  widx[p*3+2] = i2;
}

// ---------------- gather + interpolate + concat -> features (bf16, [M][384]) ----------------
// 32-lane group per point; each lane handles 8 channels (float4 loads, bf16x8 store).
__global__ __launch_bounds__(256) void k_gather(const float* __restrict__ feats_s,
                                                const float* __restrict__ feats_t,
                                                const float* __restrict__ wgt,
                                                const int* __restrict__ widx,
                                                bf16_t* __restrict__ features) {
  const int g = threadIdx.x >> 5, lane = threadIdx.x & 31;
  const int p = blockIdx.x * 8 + g;
  const int b = p >> 14;                       // N_ = 2^14
  const float w0 = wgt[p*3+0], w1 = wgt[p*3+1], w2 = wgt[p*3+2];
  const int   j0 = widx[p*3+0], j1 = widx[p*3+1], j2 = widx[p*3+2];
  const float* f0 = feats_t + ((size_t)b*S_ + j0)*DT_;
  const float* f1 = feats_t + ((size_t)b*S_ + j1)*DT_;
  const float* f2 = feats_t + ((size_t)b*S_ + j2)*DT_;
  const float* fs = feats_s + (size_t)p*DS_;
  bf16_t* out = features + (size_t)p*CIN_;
  const int c0 = lane * 8;
  if (lane < 16) {                             // skip-copy feats_s: 16 lanes x 8 ch = 128
    float4 a = *(const float4*)(fs + c0);
    float4 bv = *(const float4*)(fs + c0 + 4);
    bf16x8 o;
    o[0]=(bf16_t)a.x;  o[1]=(bf16_t)a.y;  o[2]=(bf16_t)a.z;  o[3]=(bf16_t)a.w;
    o[4]=(bf16_t)bv.x; o[5]=(bf16_t)bv.y; o[6]=(bf16_t)bv.z; o[7]=(bf16_t)bv.w;
    *(bf16x8*)(out + c0) = o;
  }
  {                                            // interp feats_t: 32 lanes x 8 ch = 256
    float4 a0 = *(const float4*)(f0 + c0), a1 = *(const float4*)(f0 + c0 + 4);
    float4 b0 = *(const float4*)(f1 + c0), b1 = *(const float4*)(f1 + c0 + 4);
    float4 cc0= *(const float4*)(f2 + c0), cc1= *(const float4*)(f2 + c0 + 4);
    bf16x8 o;
    o[0]=(bf16_t)(w0*a0.x + w1*b0.x + w2*cc0.x);
    o[1]=(bf16_t)(w0*a0.y + w1*b0.y + w2*cc0.y);
    o[2]=(bf16_t)(w0*a0.z + w1*b0.z + w2*cc0.z);
    o[3]=(bf16_t)(w0*a0.w + w1*b0.w + w2*cc0.w);
    o[4]=(bf16_t)(w0*a1.x + w1*b1.x + w2*cc1.x);
    o[5]=(bf16_t)(w0*a1.y + w1*b1.y + w2*cc1.y);
    o[6]=(bf16_t)(w0*a1.z + w1*b1.z + w2*cc1.z);
    o[7]=(bf16_t)(w0*a1.w + w1*b1.w + w2*cc1.w);
    *(bf16x8*)(out + DS_ + c0) = o;
  }
}

// ---------------- GEMM1: x0[M][256] = features[M][384] @ w0^T + b0 (bf16 MFMA) ----------------
__global__ __launch_bounds__(256) void k_gemm1(const bf16_t* __restrict__ A,
                                               const bf16_t* __restrict__ Bw,
                                               const float* __restrict__ bias,
                                               bf16_t* __restrict__ X0,
                                               float* __restrict__ psum, float* __restrict__ psq) {
  __shared__ __align__(16) bf16_t As[128*32];
  __shared__ __align__(16) bf16_t Bs[128*32];
  __shared__ float lsA[256*4], lqA[256*4];
  const int tid = threadIdx.x, w = tid >> 6, l = tid & 63;
  const int bx = blockIdx.x, by = blockIdx.y;
  const int m0 = bx*128, n0 = by*128;
  const int wr = w >> 1, wc = w & 1, l15 = l & 15, l4 = l >> 4;
  f32x4 acc[4][4];
  #pragma unroll
  for (int i = 0; i < 4; ++i)
    #pragma unroll
    for (int j = 0; j < 4; ++j) acc[i][j] = (f32x4){0.f,0.f,0.f,0.f};

  for (int step = 0; step < CIN_/32; ++step) {
    const int k0 = step*32;
    #pragma unroll
    for (int i = 0; i < 2; ++i) {
      int row = w*32 + i*16 + (l >> 2);
      int ke  = k0 + (l & 3)*8;
      gl_lds16(A  + (size_t)(m0+row)*CIN_ + ke, &As[row*32 + (l&3)*8]);
      gl_lds16(Bw + (size_t)(n0+row)*CIN_ + ke, &Bs[row*32 + (l&3)*8]);
    }
    asm volatile("s_waitcnt vmcnt(0)" ::: "memory");
    __syncthreads();
    bf16x8 af[4], bfr[4];
    #pragma unroll
    for (int mi = 0; mi < 4; ++mi) af[mi]  = *(const bf16x8*)&As[(wr*64 + mi*16 + l15)*32 + l4*8];
    #pragma unroll
    for (int ni = 0; ni < 4; ++ni) bfr[ni] = *(const bf16x8*)&Bs[(wc*64 + ni*16 + l15)*32 + l4*8];
    #pragma unroll
    for (int mi = 0; mi < 4; ++mi)
      #pragma unroll
      for (int ni = 0; ni < 4; ++ni)
        acc[mi][ni] = __builtin_amdgcn_mfma_f32_16x16x32_bf16(af[mi], bfr[ni], acc[mi][ni], 0, 0, 0);
    __syncthreads();
  }

  float ls[4] = {0,0,0,0}, lq[4] = {0,0,0,0};
  #pragma unroll
  for (int ni = 0; ni < 4; ++ni) {
    int col = n0 + wc*64 + ni*16 + l15;
    float bcol = bias[col];
    #pragma unroll
    for (int mi = 0; mi < 4; ++mi) {
      int rbase = m0 + wr*64 + mi*16 + l4*4;
      #pragma unroll
      for (int r = 0; r < 4; ++r) {
        float v = acc[mi][ni][r] + bcol;
        X0[(size_t)(rbase + r)*C0_ + col] = (bf16_t)v;
        ls[ni] += v; lq[ni] += v*v;
      }
    }
  }
  #pragma unroll
  for (int ni = 0; ni < 4; ++ni) { lsA[tid*4+ni] = ls[ni]; lqA[tid*4+ni] = lq[ni]; }
  __syncthreads();
  if (tid < 128) {
    int c = tid, wcc = c >> 6, nii = (c >> 4) & 3, ll = c & 15;
    float s = 0.f, q = 0.f;
    #pragma unroll
    for (int wrr = 0; wrr < 2; ++wrr)
      #pragma unroll
      for (int g4 = 0; g4 < 4; ++g4) {
        int t = (wrr*2 + wcc)*64 + g4*16 + ll;
        s += lsA[t*4 + nii]; q += lqA[t*4 + nii];
      }
    int pb = (bx*2 + by)*128 + c;
    psum[pb] = s; psq[pb] = q;
  }
}

// ---------------- BN0 stats finalize: one block per channel ----------------
__global__ __launch_bounds__(256) void k_fin0(const float* __restrict__ psum, const float* __restrict__ psq,
                       const float* __restrict__ gamma, const float* __restrict__ beta,
                       float* __restrict__ scale, float* __restrict__ shift) {
  __shared__ float sw[4], qw[4];
  int c = blockIdx.x, t = threadIdx.x;       // 256 blocks, 256 threads
  int nt = c >> 7, cl = c & 127;
  int ix = (t*2 + nt)*128 + cl;
  float s = psum[ix], q = psq[ix];
  #pragma unroll
  for (int o = 32; o; o >>= 1) { s += __shfl_down(s, o, 64); q += __shfl_down(q, o, 64); }
  if ((t & 63) == 0) { sw[t>>6] = s; qw[t>>6] = q; }
  __syncthreads();
  if (t == 0) {
    s = (sw[0]+sw[1])+(sw[2]+sw[3]); q = (qw[0]+qw[1])+(qw[2]+qw[3]);
    float mean = s / (float)M_;
    float var  = q / (float)M_ - mean*mean;
    float sc = gamma[c] * rsqrtf(var + 1e-5f);
    scale[c] = sc; shift[c] = beta[c] - mean*sc;
  }
}

// ---------------- GEMM2: x1[M][128] = relu(BN0(x0)) @ w1^T + b1 ----------------
__global__ __launch_bounds__(256) void k_gemm2(const bf16_t* __restrict__ X0,
                                               const bf16_t* __restrict__ Bw,
                                               const float* __restrict__ scale,
                                               const float* __restrict__ shift,
                                               const float* __restrict__ bias,
                                               bf16_t* __restrict__ X1,
                                               float* __restrict__ psum, float* __restrict__ psq) {
  __shared__ __align__(16) bf16_t As[128*32];
  __shared__ __align__(16) bf16_t Bs[128*32];
  __shared__ float scl[C0_], shl[C0_];
  __shared__ float lsA[256*4], lqA[256*4];
  const int tid = threadIdx.x, w = tid >> 6, l = tid & 63;
  const int m0 = blockIdx.x * 128;
  const int wr = w >> 1, wc = w & 1, l15 = l & 15, l4 = l >> 4;
  scl[tid] = scale[tid]; shl[tid] = shift[tid];
  f32x4 acc[4][4];
  #pragma unroll
  for (int i = 0; i < 4; ++i)
    #pragma unroll
    for (int j = 0; j < 4; ++j) acc[i][j] = (f32x4){0.f,0.f,0.f,0.f};
  __syncthreads();

  for (int step = 0; step < C0_/32; ++step) {
    const int k0 = step*32;
    #pragma unroll
    for (int i = 0; i < 2; ++i) {
      int row = w*32 + i*16 + (l >> 2);
      gl_lds16(Bw + (size_t)row*C0_ + k0 + (l&3)*8, &Bs[row*32 + (l&3)*8]);
    }
    #pragma unroll
    for (int i = 0; i < 2; ++i) {
      int ci = i*256 + tid;
      int row = ci >> 2, ke = (ci & 3)*8;
      bf16x8 v = *(const bf16x8*)(X0 + (size_t)(m0+row)*C0_ + k0 + ke);
      bf16x8 o;
      #pragma unroll
      for (int j = 0; j < 8; ++j) {
        int k = k0 + ke + j;
        float f = fmaxf(fmaf((float)v[j], scl[k], shl[k]), 0.f);
        o[j] = (bf16_t)f;
      }
      *(bf16x8*)&As[row*32 + ke] = o;
    }
    asm volatile("s_waitcnt vmcnt(0)" ::: "memory");
    __syncthreads();
    bf16x8 af[4], bfr[4];
    #pragma unroll
    for (int mi = 0; mi < 4; ++mi) af[mi]  = *(const bf16x8*)&As[(wr*64 + mi*16 + l15)*32 + l4*8];
    #pragma unroll
    for (int ni = 0; ni < 4; ++ni) bfr[ni] = *(const bf16x8*)&Bs[(wc*64 + ni*16 + l15)*32 + l4*8];
    #pragma unroll
    for (int mi = 0; mi < 4; ++mi)
      #pragma unroll
      for (int ni = 0; ni < 4; ++ni)
        acc[mi][ni] = __builtin_amdgcn_mfma_f32_16x16x32_bf16(af[mi], bfr[ni], acc[mi][ni], 0, 0, 0);
    __syncthreads();
  }

  float ls[4] = {0,0,0,0}, lq[4] = {0,0,0,0};
  #pragma unroll
  for (int ni = 0; ni < 4; ++ni) {
    int col = wc*64 + ni*16 + l15;
    float bcol = bias[col];
    #pragma unroll
    for (int mi = 0; mi < 4; ++mi) {
      int rbase = m0 + wr*64 + mi*16 + l4*4;
      #pragma unroll
      for (int r = 0; r < 4; ++r) {
        float v = acc[mi][ni][r] + bcol;
        X1[(size_t)(rbase + r)*C1_ + col] = (bf16_t)v;
        ls[ni] += v; lq[ni] += v*v;
      }
    }
  }
  #pragma unroll
  for (int ni = 0; ni < 4; ++ni) { lsA[tid*4+ni] = ls[ni]; lqA[tid*4+ni] = lq[ni]; }
  __syncthreads();
  if (tid < 128) {
    int c = tid, wcc = c >> 6, nii = (c >> 4) & 3, ll = c & 15;
    float s = 0.f, q = 0.f;
    #pragma unroll
    for (int wrr = 0; wrr < 2; ++wrr)
      #pragma unroll
      for (int g4 = 0; g4 < 4; ++g4) {
        int t = (wrr*2 + wcc)*64 + g4*16 + ll;
        s += lsA[t*4 + nii]; q += lqA[t*4 + nii];
      }
    psum[blockIdx.x*128 + c] = s; psq[blockIdx.x*128 + c] = q;
  }
}

// ---------------- BN1 stats finalize: one block per channel ----------------
__global__ __launch_bounds__(256) void k_fin1(const float* __restrict__ psum, const float* __restrict__ psq,
                       const float* __restrict__ gamma, const float* __restrict__ beta,
                       float* __restrict__ scale, float* __restrict__ shift) {
  __shared__ float sw[4], qw[4];
  int c = blockIdx.x, t = threadIdx.x;       // 128 blocks, 256 threads
  int ix = t*128 + c;
  float s = psum[ix], q = psq[ix];
  #pragma unroll
  for (int o = 32; o; o >>= 1) { s += __shfl_down(s, o, 64); q += __shfl_down(q, o, 64); }
  if ((t & 63) == 0) { sw[t>>6] = s; qw[t>>6] = q; }
  __syncthreads();
  if (t == 0) {
    s = (sw[0]+sw[1])+(sw[2]+sw[3]); q = (qw[0]+qw[1])+(qw[2]+qw[3]);
    float mean = s / (float)M_;
    float var  = q / (float)M_ - mean*mean;
    float sc = gamma[c] * rsqrtf(var + 1e-5f);
    scale[c] = sc; shift[c] = beta[c] - mean*sc;
  }
}

// ---------------- apply BN1 + ReLU -> fp32 output ----------------
__global__ __launch_bounds__(256) void k_apply(const bf16_t* __restrict__ X1,
                                               const float* __restrict__ scale,
                                               const float* __restrict__ shift,
                                               float* __restrict__ out) {
  int t = blockIdx.x * 256 + threadIdx.x;
  size_t base = (size_t)t * 8;
  bf16x8 v = *(const bf16x8*)(X1 + base);
  int c0 = (t & 15) * 8;
  #pragma unroll
  for (int j = 0; j < 8; ++j) {
    float f = fmaf((float)v[j], scale[c0+j], shift[c0+j]);
    out[base + j] = fmaxf(f, 0.f);
  }
}

extern "C" void kernel_launch(void* const* d_in, const int* in_sizes, int n_in,
                              void* d_out, int out_size, void* d_ws, size_t ws_size,
                              hipStream_t stream) {
  (void)in_sizes; (void)n_in; (void)out_size; (void)ws_size;
  const float* xyz_s   = (const float*)d_in[0];
  const float* xyz_t   = (const float*)d_in[1];
  const float* feats_s = (const float*)d_in[2];
  const float* feats_t = (const float*)d_in[3];
  const float* w0      = (const float*)d_in[4];
  const float* b0      = (const float*)d_in[5];
  const float* gamma0  = (const float*)d_in[6];
  const float* beta0   = (const float*)d_in[7];
  const float* w1      = (const float*)d_in[8];
  const float* b1      = (const float*)d_in[9];
  const float* gamma1  = (const float*)d_in[10];
  const float* beta1   = (const float*)d_in[11];
  float* out = (float*)d_out;

  char* ws = (char*)d_ws;
  size_t off = 0;
  auto alloc = [&](size_t bytes) -> void* {
    void* p = ws + off;
    off = (off + bytes + 255) & ~(size_t)255;
    return p;
  };
  float*  wgt     = (float*) alloc((size_t)M_*3*4);
  int*    widx    = (int*)   alloc((size_t)M_*3*4);
  // union region: {pd, pi} (dead after k_merge)  overlaid by  {features/x1}
  char*   uni     = (char*)  alloc((size_t)M_*CIN_*2);     // 25.2 MB >= pd+pi (12.6 MB)
  float*  pd      = (float*) uni;
  int*    pi      = (int*)  (uni + (size_t)M_*NCH_*3*4);
  bf16_t* features= (bf16_t*)uni;
  bf16_t* w0b     = (bf16_t*)alloc((size_t)C0_*CIN_*2);
  bf16_t* w1b     = (bf16_t*)alloc((size_t)C1_*C0_*2);
  bf16_t* x0      = (bf16_t*)alloc((size_t)M_*C0_*2);
  float*  psum0   = (float*) alloc(512*128*4);
  float*  psq0    = (float*) alloc(512*128*4);
  float*  scale0  = (float*) alloc(256*4);
  float*  shift0  = (float*) alloc(256*4);
  float*  psum1   = (float*) alloc(256*128*4);
  float*  psq1    = (float*) alloc(256*128*4);
  float*  scale1  = (float*) alloc(128*4);
  float*  shift1  = (float*) alloc(128*4);
  bf16_t* x1      = features;                 // features dead after gemm1 -> reuse

  k_convw <<<dim3(384), dim3(256), 0, stream>>>(w0, w1, w0b, w1b);
  k_knn   <<<dim3(N_/256, NCH_, B_), dim3(256), 0, stream>>>(xyz_s, xyz_t, pd, pi);
  k_merge <<<dim3(M_/256), dim3(256), 0, stream>>>(pd, pi, wgt, widx);
  k_gather<<<dim3(M_/8), dim3(256), 0, stream>>>(feats_s, feats_t, wgt, widx, features);
  k_gemm1 <<<dim3(M_/128, C0_/128), dim3(256), 0, stream>>>(features, w0b, b0, x0, psum0, psq0);
  k_fin0  <<<dim3(256), dim3(256), 0, stream>>>(psum0, psq0, gamma0, beta0, scale0, shift0);
  k_gemm2 <<<dim3(M_/128), dim3(256), 0, stream>>>(x0, w1b, scale0, shift0, b1, x1, psum1, psq1);
  k_fin1  <<<dim3(128), dim3(256), 0, stream>>>(psum1, psq1, gamma1, beta1, scale1, shift1);
  k_apply <<<dim3(M_*C1_/8/256), dim3(256), 0, stream>>>(x1, scale1, shift1, out);
}

// Round 4
// 137.006 us; speedup vs baseline: 2.3291x; 1.1207x over previous
//
#include <hip/hip_runtime.h>
#include <hip/hip_bf16.h>

typedef __bf16 bf16_t;
typedef __bf16 bf16x8 __attribute__((ext_vector_type(8)));
typedef float f32x4 __attribute__((ext_vector_type(4)));

#define B_   2
#define N_   16384
#define S_   4096
#define DS_  128
#define DT_  256
#define CIN_ 384
#define C0_  256
#define C1_  128
#define M_   (B_*N_)      // 32768 points total
#define NCH_ 32
#define SCH_ (S_/NCH_)    // 128 targets per chunk

__device__ __forceinline__ void gl_lds16(const void* g, void* l) {
  __builtin_amdgcn_global_load_lds((const __attribute__((address_space(1))) void*)g,
                                   (__attribute__((address_space(3))) void*)l, 16, 0, 0);
}

// branchy top-3 insert with exact lexicographic (d, idx) strict-less (small merges only)
__device__ __forceinline__ void lins3(float d, int ix,
                                      float& d0, float& d1, float& d2,
                                      int& i0, int& i1, int& i2) {
  if (d < d2 || (d == d2 && ix < i2)) {
    d2 = d; i2 = ix;
    if (d2 < d1 || (d2 == d1 && i2 < i1)) {
      float td = d1; d1 = d2; d2 = td; int ti = i1; i1 = i2; i2 = ti;
      if (d1 < d0 || (d1 == d0 && i1 < i0)) {
        td = d0; d0 = d1; d1 = td; ti = i0; i0 = i1; i1 = ti;
      }
    }
  }
}

// branchless sorted-insert: distances via min/med3, indices via cmp-on-old-state.
// strict < + ascending candidate index => top_k-stable.
__device__ __forceinline__ void bins3(float d, int jx,
                                      float& e0, float& e1, float& e2,
                                      int& x0, int& x1, int& x2) {
  int t2i = (d < e1) ? x1 : jx;
  int nI2 = (d < e2) ? t2i : x2;
  int t1i = (d < e0) ? x0 : jx;
  int nI1 = (d < e1) ? t1i : x1;
  int nI0 = (d < e0) ? jx  : x0;
  float nD2 = __builtin_amdgcn_fmed3f(e1, e2, d);
  float nD1 = __builtin_amdgcn_fmed3f(e0, e1, d);
  float nD0 = fminf(e0, d);
  x0 = nI0; x1 = nI1; x2 = nI2;
  e0 = nD0; e1 = nD1; e2 = nD2;
}

// ---------------- weights fp32 -> bf16 ----------------
__global__ void k_convw(const float* __restrict__ w0, const float* __restrict__ w1,
                        bf16_t* __restrict__ w0b, bf16_t* __restrict__ w1b) {
  int i = blockIdx.x * 256 + threadIdx.x;
  if (i < C0_*CIN_) w0b[i] = (bf16_t)w0[i];
  if (i < C1_*C0_)  w1b[i] = (bf16_t)w1[i];
}

// ---------------- pack targets: (x,y,z,t2) ----------------
__global__ void k_prep(const float* __restrict__ xyz_t, float4* __restrict__ tgt4) {
  int i = blockIdx.x * 256 + threadIdx.x;          // B_*S_ = 8192
  const float* q = xyz_t + (size_t)i*3;
  float x = q[0], y = q[1], z = q[2];
  float t2 = __fadd_rn(__fadd_rn(__fmul_rn(x,x), __fmul_rn(y,y)), __fmul_rn(z,z));
  tgt4[i] = make_float4(x, y, z, t2);
}

// ---------------- 3-NN over one target chunk ----------------
// Exact numpy fp32 order: d = (s2 + t2) - 2*((sx tx + sy ty) + sz tz)
// Targets read via wave-uniform address -> s_load into SGPRs (no LDS, no barrier).
__global__ __launch_bounds__(256) void k_knn(const float* __restrict__ xyz_s,
                                             const float4* __restrict__ tgt4,
                                             float* __restrict__ pd, int* __restrict__ pi) {
  const int b = blockIdx.z, ch = blockIdx.y;
  const int n = blockIdx.x * 256 + threadIdx.x;
  const int s0 = ch * SCH_;
  const float4* tp = tgt4 + (size_t)b*S_ + s0;     // uniform base
  const float* ps = xyz_s + ((size_t)b*N_ + n)*3;
  const float sx = ps[0], sy = ps[1], sz = ps[2];
  const float s2 = __fadd_rn(__fadd_rn(__fmul_rn(sx,sx), __fmul_rn(sy,sy)), __fmul_rn(sz,sz));

  float D0[4], D1[4], D2[4];
  int   I0[4], I1[4], I2[4];
  #pragma unroll
  for (int c = 0; c < 4; ++c) { D0[c]=D1[c]=D2[c]=3.4e38f; I0[c]=I1[c]=I2[c]=0; }

  #pragma unroll 4
  for (int t = 0; t < SCH_/4; ++t) {
    #pragma unroll
    for (int c = 0; c < 4; ++c) {
      const int j = t*4 + c;
      float4 tg = tp[j];                           // uniform -> scalar load
      float dot = __fadd_rn(__fadd_rn(__fmul_rn(sx,tg.x), __fmul_rn(sy,tg.y)), __fmul_rn(sz,tg.z));
      float d   = __fsub_rn(__fadd_rn(s2, tg.w), __fmul_rn(2.f, dot));
      bins3(d, j, D0[c], D1[c], D2[c], I0[c], I1[c], I2[c]);
    }
  }

  // merge 4 chains (12 candidates) with exact lexicographic comparator
  float e0 = D0[0], e1 = D1[0], e2 = D2[0];
  int   x0 = I0[0], x1 = I1[0], x2 = I2[0];
  #pragma unroll
  for (int c = 1; c < 4; ++c) {
    lins3(D0[c], I0[c], e0, e1, e2, x0, x1, x2);
    lins3(D1[c], I1[c], e0, e1, e2, x0, x1, x2);
    lins3(D2[c], I2[c], e0, e1, e2, x0, x1, x2);
  }

  // chunk-major layout: fully coalesced writes (and coalesced merge reads)
  size_t base = ((size_t)ch*M_ + (size_t)b*N_ + n)*3;
  pd[base+0] = e0; pd[base+1] = e1; pd[base+2] = e2;
  pi[base+0] = s0+x0; pi[base+1] = s0+x1; pi[base+2] = s0+x2;
}

// ---------------- merge chunk candidates, compute inverse-distance weights ----------------
__global__ void k_merge(const float* __restrict__ pd, const int* __restrict__ pi,
                        float* __restrict__ wgt, int* __restrict__ widx) {
  int p = blockIdx.x * 256 + threadIdx.x;  // 0..32767
  float e0 = 3.4e38f, e1 = 3.4e38f, e2 = 3.4e38f;
  int   x0 = 0, x1 = 0, x2 = 0;
  for (int ch = 0; ch < NCH_; ++ch) {      // ascending chunk = ascending target index
    size_t base = ((size_t)ch*M_ + p)*3;
    #pragma unroll
    for (int k = 0; k < 3; ++k)
      bins3(pd[base+k], pi[base+k], e0, e1, e2, x0, x1, x2);
  }
  float r0 = 1.f/(e0 + 1e-8f), r1 = 1.f/(e1 + 1e-8f), r2 = 1.f/(e2 + 1e-8f);
  float s = r0 + r1 + r2;
  wgt[p*3+0] = r0/s; wgt[p*3+1] = r1/s; wgt[p*3+2] = r2/s;
  widx[p*3+0] = x0;  widx[p*3+1] = x1;  widx[p*3+2] = x2;
}

// ---------------- gather + interpolate + concat -> features (bf16, [M][384]) ----------------
__global__ __launch_bounds__(256) void k_gather(const float* __restrict__ feats_s,
                                                const float* __restrict__ feats_t,
                                                const float* __restrict__ wgt,
                                                const int* __restrict__ widx,
                                                bf16_t* __restrict__ features) {
  const int g = threadIdx.x >> 5, lane = threadIdx.x & 31;
  const int p = blockIdx.x * 8 + g;
  const int b = p >> 14;                       // N_ = 2^14
  const float w0 = wgt[p*3+0], w1 = wgt[p*3+1], w2 = wgt[p*3+2];
  const int   j0 = widx[p*3+0], j1 = widx[p*3+1], j2 = widx[p*3+2];
  const float* f0 = feats_t + ((size_t)b*S_ + j0)*DT_;
  const float* f1 = feats_t + ((size_t)b*S_ + j1)*DT_;
  const float* f2 = feats_t + ((size_t)b*S_ + j2)*DT_;
  const float* fs = feats_s + (size_t)p*DS_;
  bf16_t* out = features + (size_t)p*CIN_;
  const int c0 = lane * 8;
  if (lane < 16) {
    float4 a = *(const float4*)(fs + c0);
    float4 bv = *(const float4*)(fs + c0 + 4);
    bf16x8 o;
    o[0]=(bf16_t)a.x;  o[1]=(bf16_t)a.y;  o[2]=(bf16_t)a.z;  o[3]=(bf16_t)a.w;
    o[4]=(bf16_t)bv.x; o[5]=(bf16_t)bv.y; o[6]=(bf16_t)bv.z; o[7]=(bf16_t)bv.w;
    *(bf16x8*)(out + c0) = o;
  }
  {
    float4 a0 = *(const float4*)(f0 + c0), a1 = *(const float4*)(f0 + c0 + 4);
    float4 b0 = *(const float4*)(f1 + c0), b1 = *(const float4*)(f1 + c0 + 4);
    float4 cc0= *(const float4*)(f2 + c0), cc1= *(const float4*)(f2 + c0 + 4);
    bf16x8 o;
    o[0]=(bf16_t)(w0*a0.x + w1*b0.x + w2*cc0.x);
    o[1]=(bf16_t)(w0*a0.y + w1*b0.y + w2*cc0.y);
    o[2]=(bf16_t)(w0*a0.z + w1*b0.z + w2*cc0.z);
    o[3]=(bf16_t)(w0*a0.w + w1*b0.w + w2*cc0.w);
    o[4]=(bf16_t)(w0*a1.x + w1*b1.x + w2*cc1.x);
    o[5]=(bf16_t)(w0*a1.y + w1*b1.y + w2*cc1.y);
    o[6]=(bf16_t)(w0*a1.z + w1*b1.z + w2*cc1.z);
    o[7]=(bf16_t)(w0*a1.w + w1*b1.w + w2*cc1.w);
    *(bf16x8*)(out + DS_ + c0) = o;
  }
}

// ---------------- GEMM1: x0[M][256] = features[M][384] @ w0^T + b0 (bf16 MFMA) ----------------
__global__ __launch_bounds__(256) void k_gemm1(const bf16_t* __restrict__ A,
                                               const bf16_t* __restrict__ Bw,
                                               const float* __restrict__ bias,
                                               bf16_t* __restrict__ X0,
                                               float* __restrict__ psum, float* __restrict__ psq) {
  __shared__ __align__(16) bf16_t As[128*32];
  __shared__ __align__(16) bf16_t Bs[128*32];
  __shared__ float lsA[256*4], lqA[256*4];
  const int tid = threadIdx.x, w = tid >> 6, l = tid & 63;
  const int bx = blockIdx.x, by = blockIdx.y;
  const int m0 = bx*128, n0 = by*128;
  const int wr = w >> 1, wc = w & 1, l15 = l & 15, l4 = l >> 4;
  f32x4 acc[4][4];
  #pragma unroll
  for (int i = 0; i < 4; ++i)
    #pragma unroll
    for (int j = 0; j < 4; ++j) acc[i][j] = (f32x4){0.f,0.f,0.f,0.f};

  for (int step = 0; step < CIN_/32; ++step) {
    const int k0 = step*32;
    #pragma unroll
    for (int i = 0; i < 2; ++i) {
      int row = w*32 + i*16 + (l >> 2);
      int ke  = k0 + (l & 3)*8;
      gl_lds16(A  + (size_t)(m0+row)*CIN_ + ke, &As[row*32 + (l&3)*8]);
      gl_lds16(Bw + (size_t)(n0+row)*CIN_ + ke, &Bs[row*32 + (l&3)*8]);
    }
    asm volatile("s_waitcnt vmcnt(0)" ::: "memory");
    __syncthreads();
    bf16x8 af[4], bfr[4];
    #pragma unroll
    for (int mi = 0; mi < 4; ++mi) af[mi]  = *(const bf16x8*)&As[(wr*64 + mi*16 + l15)*32 + l4*8];
    #pragma unroll
    for (int ni = 0; ni < 4; ++ni) bfr[ni] = *(const bf16x8*)&Bs[(wc*64 + ni*16 + l15)*32 + l4*8];
    #pragma unroll
    for (int mi = 0; mi < 4; ++mi)
      #pragma unroll
      for (int ni = 0; ni < 4; ++ni)
        acc[mi][ni] = __builtin_amdgcn_mfma_f32_16x16x32_bf16(af[mi], bfr[ni], acc[mi][ni], 0, 0, 0);
    __syncthreads();
  }

  float ls[4] = {0,0,0,0}, lq[4] = {0,0,0,0};
  #pragma unroll
  for (int ni = 0; ni < 4; ++ni) {
    int col = n0 + wc*64 + ni*16 + l15;
    float bcol = bias[col];
    #pragma unroll
    for (int mi = 0; mi < 4; ++mi) {
      int rbase = m0 + wr*64 + mi*16 + l4*4;
      #pragma unroll
      for (int r = 0; r < 4; ++r) {
        float v = acc[mi][ni][r] + bcol;
        X0[(size_t)(rbase + r)*C0_ + col] = (bf16_t)v;
        ls[ni] += v; lq[ni] += v*v;
      }
    }
  }
  #pragma unroll
  for (int ni = 0; ni < 4; ++ni) { lsA[tid*4+ni] = ls[ni]; lqA[tid*4+ni] = lq[ni]; }
  __syncthreads();
  if (tid < 128) {
    int c = tid, wcc = c >> 6, nii = (c >> 4) & 3, ll = c & 15;
    float s = 0.f, q = 0.f;
    #pragma unroll
    for (int wrr = 0; wrr < 2; ++wrr)
      #pragma unroll
      for (int g4 = 0; g4 < 4; ++g4) {
        int t = (wrr*2 + wcc)*64 + g4*16 + ll;
        s += lsA[t*4 + nii]; q += lqA[t*4 + nii];
      }
    int pb = (bx*2 + by)*128 + c;
    psum[pb] = s; psq[pb] = q;
  }
}

// ---------------- BN0 stats finalize: one block per channel ----------------
__global__ __launch_bounds__(256) void k_fin0(const float* __restrict__ psum, const float* __restrict__ psq,
                       const float* __restrict__ gamma, const float* __restrict__ beta,
                       float* __restrict__ scale, float* __restrict__ shift) {
  __shared__ float sw[4], qw[4];
  int c = blockIdx.x, t = threadIdx.x;       // 256 blocks, 256 threads
  int nt = c >> 7, cl = c & 127;
  int ix = (t*2 + nt)*128 + cl;
  float s = psum[ix], q = psq[ix];
  #pragma unroll
  for (int o = 32; o; o >>= 1) { s += __shfl_down(s, o, 64); q += __shfl_down(q, o, 64); }
  if ((t & 63) == 0) { sw[t>>6] = s; qw[t>>6] = q; }
  __syncthreads();
  if (t == 0) {
    s = (sw[0]+sw[1])+(sw[2]+sw[3]); q = (qw[0]+qw[1])+(qw[2]+qw[3]);
    float mean = s / (float)M_;
    float var  = q / (float)M_ - mean*mean;
    float sc = gamma[c] * rsqrtf(var + 1e-5f);
    scale[c] = sc; shift[c] = beta[c] - mean*sc;
  }
}

// ---------------- GEMM2: x1[M][128] = relu(BN0(x0)) @ w1^T + b1 ----------------
__global__ __launch_bounds__(256) void k_gemm2(const bf16_t* __restrict__ X0,
                                               const bf16_t* __restrict__ Bw,
                                               const float* __restrict__ scale,
                                               const float* __restrict__ shift,
                                               const float* __restrict__ bias,
                                               bf16_t* __restrict__ X1,
                                               float* __restrict__ psum, float* __restrict__ psq) {
  __shared__ __align__(16) bf16_t As[128*32];
  __shared__ __align__(16) bf16_t Bs[128*32];
  __shared__ float scl[C0_], shl[C0_];
  __shared__ float lsA[256*4], lqA[256*4];
  const int tid = threadIdx.x, w = tid >> 6, l = tid & 63;
  const int m0 = blockIdx.x * 128;
  const int wr = w >> 1, wc = w & 1, l15 = l & 15, l4 = l >> 4;
  scl[tid] = scale[tid]; shl[tid] = shift[tid];
  f32x4 acc[4][4];
  #pragma unroll
  for (int i = 0; i < 4; ++i)
    #pragma unroll
    for (int j = 0; j < 4; ++j) acc[i][j] = (f32x4){0.f,0.f,0.f,0.f};
  __syncthreads();

  for (int step = 0; step < C0_/32; ++step) {
    const int k0 = step*32;
    #pragma unroll
    for (int i = 0; i < 2; ++i) {
      int row = w*32 + i*16 + (l >> 2);
      gl_lds16(Bw + (size_t)row*C0_ + k0 + (l&3)*8, &Bs[row*32 + (l&3)*8]);
    }
    #pragma unroll
    for (int i = 0; i < 2; ++i) {
      int ci = i*256 + tid;
      int row = ci >> 2, ke = (ci & 3)*8;
      bf16x8 v = *(const bf16x8*)(X0 + (size_t)(m0+row)*C0_ + k0 + ke);
      bf16x8 o;
      #pragma unroll
      for (int j = 0; j < 8; ++j) {
        int k = k0 + ke + j;
        float f = fmaxf(fmaf((float)v[j], scl[k], shl[k]), 0.f);
        o[j] = (bf16_t)f;
      }
      *(bf16x8*)&As[row*32 + ke] = o;
    }
    asm volatile("s_waitcnt vmcnt(0)" ::: "memory");
    __syncthreads();
    bf16x8 af[4], bfr[4];
    #pragma unroll
    for (int mi = 0; mi < 4; ++mi) af[mi]  = *(const bf16x8*)&As[(wr*64 + mi*16 + l15)*32 + l4*8];
    #pragma unroll
    for (int ni = 0; ni < 4; ++ni) bfr[ni] = *(const bf16x8*)&Bs[(wc*64 + ni*16 + l15)*32 + l4*8];
    #pragma unroll
    for (int mi = 0; mi < 4; ++mi)
      #pragma unroll
      for (int ni = 0; ni < 4; ++ni)
        acc[mi][ni] = __builtin_amdgcn_mfma_f32_16x16x32_bf16(af[mi], bfr[ni], acc[mi][ni], 0, 0, 0);
    __syncthreads();
  }

  float ls[4] = {0,0,0,0}, lq[4] = {0,0,0,0};
  #pragma unroll
  for (int ni = 0; ni < 4; ++ni) {
    int col = wc*64 + ni*16 + l15;
    float bcol = bias[col];
    #pragma unroll
    for (int mi = 0; mi < 4; ++mi) {
      int rbase = m0 + wr*64 + mi*16 + l4*4;
      #pragma unroll
      for (int r = 0; r < 4; ++r) {
        float v = acc[mi][ni][r] + bcol;
        X1[(size_t)(rbase + r)*C1_ + col] = (bf16_t)v;
        ls[ni] += v; lq[ni] += v*v;
      }
    }
  }
  #pragma unroll
  for (int ni = 0; ni < 4; ++ni) { lsA[tid*4+ni] = ls[ni]; lqA[tid*4+ni] = lq[ni]; }
  __syncthreads();
  if (tid < 128) {
    int c = tid, wcc = c >> 6, nii = (c >> 4) & 3, ll = c & 15;
    float s = 0.f, q = 0.f;
    #pragma unroll
    for (int wrr = 0; wrr < 2; ++wrr)
      #pragma unroll
      for (int g4 = 0; g4 < 4; ++g4) {
        int t = (wrr*2 + wcc)*64 + g4*16 + ll;
        s += lsA[t*4 + nii]; q += lqA[t*4 + nii];
      }
    psum[blockIdx.x*128 + c] = s; psq[blockIdx.x*128 + c] = q;
  }
}

// ---------------- BN1 stats finalize: one block per channel ----------------
__global__ __launch_bounds__(256) void k_fin1(const float* __restrict__ psum, const float* __restrict__ psq,
                       const float* __restrict__ gamma, const float* __restrict__ beta,
                       float* __restrict__ scale, float* __restrict__ shift) {
  __shared__ float sw[4], qw[4];
  int c = blockIdx.x, t = threadIdx.x;       // 128 blocks, 256 threads
  int ix = t*128 + c;
  float s = psum[ix], q = psq[ix];
  #pragma unroll
  for (int o = 32; o; o >>= 1) { s += __shfl_down(s, o, 64); q += __shfl_down(q, o, 64); }
  if ((t & 63) == 0) { sw[t>>6] = s; qw[t>>6] = q; }
  __syncthreads();
  if (t == 0) {
    s = (sw[0]+sw[1])+(sw[2]+sw[3]); q = (qw[0]+qw[1])+(qw[2]+qw[3]);
    float mean = s / (float)M_;
    float var  = q / (float)M_ - mean*mean;
    float sc = gamma[c] * rsqrtf(var + 1e-5f);
    scale[c] = sc; shift[c] = beta[c] - mean*sc;
  }
}

// ---------------- apply BN1 + ReLU -> fp32 output ----------------
__global__ __launch_bounds__(256) void k_apply(const bf16_t* __restrict__ X1,
                                               const float* __restrict__ scale,
                                               const float* __restrict__ shift,
                                               float* __restrict__ out) {
  int t = blockIdx.x * 256 + threadIdx.x;
  size_t base = (size_t)t * 8;
  bf16x8 v = *(const bf16x8*)(X1 + base);
  int c0 = (t & 15) * 8;
  #pragma unroll
  for (int j = 0; j < 8; ++j) {
    float f = fmaf((float)v[j], scale[c0+j], shift[c0+j]);
    out[base + j] = fmaxf(f, 0.f);
  }
}

extern "C" void kernel_launch(void* const* d_in, const int* in_sizes, int n_in,
                              void* d_out, int out_size, void* d_ws, size_t ws_size,
                              hipStream_t stream) {
  (void)in_sizes; (void)n_in; (void)out_size; (void)ws_size;
  const float* xyz_s   = (const float*)d_in[0];
  const float* xyz_t   = (const float*)d_in[1];
  const float* feats_s = (const float*)d_in[2];
  const float* feats_t = (const float*)d_in[3];
  const float* w0      = (const float*)d_in[4];
  const float* b0      = (const float*)d_in[5];
  const float* gamma0  = (const float*)d_in[6];
  const float* beta0   = (const float*)d_in[7];
  const float* w1      = (const float*)d_in[8];
  const float* b1      = (const float*)d_in[9];
  const float* gamma1  = (const float*)d_in[10];
  const float* beta1   = (const float*)d_in[11];
  float* out = (float*)d_out;

  char* ws = (char*)d_ws;
  size_t off = 0;
  auto alloc = [&](size_t bytes) -> void* {
    void* p = ws + off;
    off = (off + bytes + 255) & ~(size_t)255;
    return p;
  };
  float*  wgt     = (float*) alloc((size_t)M_*3*4);
  int*    widx    = (int*)   alloc((size_t)M_*3*4);
  float4* tgt4    = (float4*)alloc((size_t)B_*S_*16);
  // union region: {pd, pi} (dead after k_merge) overlaid by {features/x1}
  // pd+pi = M_*NCH_*3*4*2 = M_*768 = M_*CIN_*2 bytes exactly
  char*   uni     = (char*)  alloc((size_t)M_*CIN_*2);
  float*  pd      = (float*) uni;
  int*    pi      = (int*)  (uni + (size_t)M_*NCH_*3*4);
  bf16_t* features= (bf16_t*)uni;
  bf16_t* w0b     = (bf16_t*)alloc((size_t)C0_*CIN_*2);
  bf16_t* w1b     = (bf16_t*)alloc((size_t)C1_*C0_*2);
  bf16_t* x0      = (bf16_t*)alloc((size_t)M_*C0_*2);
  float*  psum0   = (float*) alloc(512*128*4);
  float*  psq0    = (float*) alloc(512*128*4);
  float*  scale0  = (float*) alloc(256*4);
  float*  shift0  = (float*) alloc(256*4);
  float*  psum1   = (float*) alloc(256*128*4);
  float*  psq1    = (float*) alloc(256*128*4);
  float*  scale1  = (float*) alloc(128*4);
  float*  shift1  = (float*) alloc(128*4);
  bf16_t* x1      = features;                 // features dead after gemm1 -> reuse

  k_convw <<<dim3(384), dim3(256), 0, stream>>>(w0, w1, w0b, w1b);
  k_prep  <<<dim3(B_*S_/256), dim3(256), 0, stream>>>(xyz_t, tgt4);
  k_knn   <<<dim3(N_/256, NCH_, B_), dim3(256), 0, stream>>>(xyz_s, tgt4, pd, pi);
  k_merge <<<dim3(M_/256), dim3(256), 0, stream>>>(pd, pi, wgt, widx);
  k_gather<<<dim3(M_/8), dim3(256), 0, stream>>>(feats_s, feats_t, wgt, widx, features);
  k_gemm1 <<<dim3(M_/128, C0_/128), dim3(256), 0, stream>>>(features, w0b, b0, x0, psum0, psq0);
  k_fin0  <<<dim3(256), dim3(256), 0, stream>>>(psum0, psq0, gamma0, beta0, scale0, shift0);
  k_gemm2 <<<dim3(M_/128), dim3(256), 0, stream>>>(x0, w1b, scale0, shift0, b1, x1, psum1, psq1);
  k_fin1  <<<dim3(128), dim3(256), 0, stream>>>(psum1, psq1, gamma1, beta1, scale1, shift1);
  k_apply <<<dim3(M_*C1_/8/256), dim3(256), 0, stream>>>(x1, scale1, shift1, out);
}